// Round 1
// baseline (4506.300 us; speedup 1.0000x reference)
//
#include <hip/hip_runtime.h>
#include <cstddef>
#include <cstdint>

namespace {

constexpr int NPROT = 100000;
constexpr int EPROT = 1600000;
constexpr int NLIG  = 5000;
constexpr int ELIG  = 80000;

// ---------------- CSR construction ----------------

__global__ void hist_kernel(const int* __restrict__ dst, int* __restrict__ cnt, int e) {
  int i = blockIdx.x * 256 + threadIdx.x;
  if (i < e) atomicAdd(&cnt[dst[i]], 1);
}

__global__ void norm_kernel(const int* __restrict__ cnt, float* __restrict__ nrm, int n) {
  int i = blockIdx.x * 256 + threadIdx.x;
  if (i < n) nrm[i] = 1.0f / sqrtf(fmaxf((float)cnt[i], 1.0f));
}

// single-block exclusive scan (n up to ~1M is fine; each thread owns a chunk)
__global__ void exscan_kernel(const int* __restrict__ in, int* __restrict__ out, int n) {
  __shared__ int sums[1024];
  int t = threadIdx.x;
  int chunk = (n + 1023) >> 10;
  int beg = t * chunk;
  int end = beg + chunk; if (end > n) end = n;
  int s = 0;
  for (int i = beg; i < end; ++i) s += in[i];
  sums[t] = s;
  __syncthreads();
  int val = s;
  for (int off = 1; off < 1024; off <<= 1) {
    int add = (t >= off) ? sums[t - off] : 0;
    __syncthreads();
    val += add;
    sums[t] = val;
    __syncthreads();
  }
  int run = val - s;  // exclusive prefix of this thread's chunk
  for (int i = beg; i < end; ++i) { out[i] = run; run += in[i]; }
  if (t == 1023) out[n] = val;
}

__global__ void scatter_kernel(const int* __restrict__ src, const int* __restrict__ dst,
                               const int* __restrict__ rp, int* __restrict__ cur,
                               int* __restrict__ col, int e) {
  int i = blockIdx.x * 256 + threadIdx.x;
  if (i < e) {
    int d = dst[i];
    int p = rp[d] + atomicAdd(&cur[d], 1);
    col[p] = src[i];
  }
}

// ---------------- GNN kernels ----------------
// Carry g_k = norm .* h_k.  Hop: s_k[v] = sum_{e: dst=v} g_{k-1}[src[e]]
//   h_k = norm .* s_k ;  g_k = norm^2 .* s_k
// y = b + sum_k h_k @ W[k*din:(k+1)*din]

// one wave (64 lanes) per node, lane = feature; 4 nodes per 256-thread block
template<int DIN>
__global__ void gather_kernel(const float* __restrict__ g, const int* __restrict__ rp,
                              const int* __restrict__ col, float* __restrict__ outb, int n) {
  int wv = threadIdx.x >> 6, lane = threadIdx.x & 63;
  int v = blockIdx.x * 4 + wv;
  if (v >= n) return;
  int beg = rp[v], end = rp[v + 1];
  float a0 = 0.f, a1 = 0.f;
  for (int e = beg; e < end; ++e) {
    int s = col[e];
    const float* row = g + (size_t)s * DIN;
    if (lane < DIN) a0 += row[lane];
    if (DIN > 64) { if (lane + 64 < DIN) a1 += row[lane + 64]; }
  }
  float* o = outb + (size_t)v * DIN;
  if (lane < DIN) o[lane] = a0;
  if (DIN > 64) { if (lane + 64 < DIN) o[lane + 64] = a1; }
}

// fused: read src row (s_k, or x for INIT), write g into A, accumulate y += h @ W_k
template<int DIN, int DOUT, bool INIT, bool WRITEG>
__global__ void hop_gemm_kernel(const float* __restrict__ src, const float* __restrict__ nrm,
                                const float* __restrict__ W, const float* __restrict__ bias,
                                float* __restrict__ A, float* __restrict__ y,
                                int k, int n) {
  __shared__ float h[4][DIN];
  int wv = threadIdx.x >> 6, lane = threadIdx.x & 63;
  int v = blockIdx.x * 4 + wv;
  bool ok = (v < n);
  float nm = ok ? nrm[v] : 0.f;
  if (ok) {
    const float* srow = src + (size_t)v * DIN;
    for (int f = lane; f < DIN; f += 64) {
      float s = srow[f];
      float hv = INIT ? s : s * nm;
      h[wv][f] = hv;
      if (WRITEG) A[(size_t)v * DIN + f] = INIT ? s * nm : hv * nm;
    }
  }
  __syncthreads();
  if (ok && lane < DOUT) {
    float acc = INIT ? bias[lane] : y[(size_t)v * DOUT + lane];
    const float* Wk = W + (size_t)k * DIN * DOUT + lane;
    #pragma unroll 2
    for (int f = 0; f < DIN; ++f)
      acc += h[wv][f] * Wk[(size_t)f * DOUT];
    y[(size_t)v * DOUT + lane] = acc;
  }
}

template<int DOUT>
__global__ void relu_l2norm_kernel(const float* __restrict__ y, float* __restrict__ X, int n) {
  int wv = threadIdx.x >> 6, lane = threadIdx.x & 63;
  int v = blockIdx.x * 4 + wv;
  if (v >= n) return;
  float val = 0.f;
  if (lane < DOUT) val = fmaxf(y[(size_t)v * DOUT + lane], 0.f);
  float ss = val * val;
  #pragma unroll
  for (int off = 32; off > 0; off >>= 1) ss += __shfl_xor(ss, off, 64);
  float scale = 1.f / fmaxf(sqrtf(ss), 1e-12f);
  if (lane < DOUT) X[(size_t)v * DOUT + lane] = val * scale;
}

// values are >= 0 (post relu+l2norm), so uint atomicMax == float max; rep must be zeroed
__global__ void segmax_kernel(const float* __restrict__ X, const int* __restrict__ gid,
                              float* __restrict__ rep, int n, int row_off) {
  int idx = blockIdx.x * 256 + threadIdx.x;
  int total = n * 45;
  if (idx >= total) return;
  int v = idx / 45, j = idx - v * 45;
  float val = X[idx];
  atomicMax((unsigned int*)&rep[(size_t)(row_off + gid[v]) * 45 + j], __float_as_uint(val));
}

// ---------------- attention ----------------

__global__ void qkv_kernel(const float* __restrict__ rep, const float* __restrict__ w,
                           const float* __restrict__ b, float* __restrict__ qkv) {
  int i = blockIdx.x;      // 0..129
  int t = threadIdx.x;     // 256
  __shared__ float sr[45];
  if (t < 45) sr[t] = (i < 65) ? rep[(size_t)i * 45 + t] : 0.f;
  __syncthreads();
  if (t < 135) {
    float acc = b[t];
    #pragma unroll 5
    for (int d = 0; d < 45; ++d) acc += sr[d] * w[d * 135 + t];
    qkv[(size_t)i * 135 + t] = acc;
  }
}

__global__ void attn_kernel(const float* __restrict__ qkv, const float* __restrict__ proj_w,
                            const float* __restrict__ proj_b, float* __restrict__ ctx) {
  int i = blockIdx.x;     // query row
  int t = threadIdx.x;    // 256
  __shared__ float q[45];
  __shared__ float p[130];
  __shared__ float red[256];
  __shared__ float ao[45];
  if (t < 45) q[t] = qkv[(size_t)i * 135 + t];
  __syncthreads();
  float s = -1e30f;
  if (t < 130) {
    int j = t;
    float dot = 0.f;
    #pragma unroll 5
    for (int d = 0; d < 45; ++d) dot += q[d] * qkv[(size_t)j * 135 + 45 + d];
    dot *= 0.14907119849998599f;  // 45^-0.5
    bool mz;  // mask == 0 ?
    if (i == 64 && j == 64) mz = true;
    else if (i == 64 || j == 64) mz = false;
    else mz = !(i == j && i < 65);
    s = mz ? -1e9f : dot;
  }
  red[t] = s;
  __syncthreads();
  #pragma unroll
  for (int off = 128; off > 0; off >>= 1) {
    if (t < off) red[t] = fmaxf(red[t], red[t + off]);
    __syncthreads();
  }
  float mx = red[0];
  __syncthreads();
  float e = (t < 130) ? expf(s - mx) : 0.f;
  red[t] = e;
  __syncthreads();
  #pragma unroll
  for (int off = 128; off > 0; off >>= 1) {
    if (t < off) red[t] += red[t + off];
    __syncthreads();
  }
  float denom = red[0];
  __syncthreads();
  if (t < 130) p[t] = e / denom;
  __syncthreads();
  if (t < 45) {
    float acc = 0.f;
    for (int j = 0; j < 130; ++j) acc += p[j] * qkv[(size_t)j * 135 + 90 + t];
    ao[t] = acc;
  }
  __syncthreads();
  if (t < 45) {
    float pr = proj_b[t];
    #pragma unroll 5
    for (int e2 = 0; e2 < 45; ++e2) pr += ao[e2] * proj_w[e2 * 45 + t];
    ctx[(size_t)i * 45 + t] = pr;
  }
}

// ---------------- head MLP ----------------

__global__ void bias_init_kernel(const float* __restrict__ b, float* __restrict__ out, int n) {
  int i = blockIdx.x * 256 + threadIdx.x;
  if (i < n) out[i] = b[i];
}

template<bool RELU_IN>
__global__ void fc_splitk_kernel(const float* __restrict__ x, const float* __restrict__ W,
                                 float* __restrict__ out, int nin, int nout, int kchunk) {
  __shared__ float xs[1024];
  int k0 = blockIdx.y * kchunk;
  int k1 = k0 + kchunk; if (k1 > nin) k1 = nin;
  int len = k1 - k0;
  for (int i = threadIdx.x; i < len; i += blockDim.x) {
    float v = x[k0 + i];
    xs[i] = RELU_IN ? fmaxf(v, 0.f) : v;
  }
  __syncthreads();
  int j = blockIdx.x * blockDim.x + threadIdx.x;
  if (j < nout) {
    float acc = 0.f;
    const float* Wp = W + (size_t)k0 * nout + j;
    for (int i = 0; i < len; ++i) acc += xs[i] * Wp[(size_t)i * nout];
    atomicAdd(&out[j], acc);
  }
}

__global__ void final_fc_kernel(const float* __restrict__ x, const float* __restrict__ W,
                                const float* __restrict__ b, float* __restrict__ out) {
  __shared__ float red[512];
  int t = threadIdx.x;
  float acc = 0.f;
  if (t < 500) acc = fmaxf(x[t], 0.f) * W[t];
  red[t] = acc;
  __syncthreads();
  #pragma unroll
  for (int off = 256; off > 0; off >>= 1) {
    if (t < off) red[t] += red[t + off];
    __syncthreads();
  }
  if (t == 0) {
    float z = red[0] + b[0];
    out[0] = 1.f / (1.f + expf(-z));
  }
}

// ---------------- host-side orchestration ----------------

struct GnnBufs {
  float *A, *B, *X, *Y, *nrm;
  int *cnt, *cur, *rp, *col;
};

template<int DIN, int DOUT>
void run_layer(const float* xin, const GnnBufs& g, const float* W, const float* b,
               int n, hipStream_t st) {
  int nb = (n + 3) / 4;
  hop_gemm_kernel<DIN, DOUT, true, true><<<nb, 256, 0, st>>>(xin, g.nrm, W, b, g.A, g.Y, 0, n);
  for (int k = 1; k <= 4; ++k) {
    gather_kernel<DIN><<<nb, 256, 0, st>>>(g.A, g.rp, g.col, g.B, n);
    if (k < 4)
      hop_gemm_kernel<DIN, DOUT, false, true><<<nb, 256, 0, st>>>(g.B, g.nrm, W, b, g.A, g.Y, k, n);
    else
      hop_gemm_kernel<DIN, DOUT, false, false><<<nb, 256, 0, st>>>(g.B, g.nrm, W, b, g.A, g.Y, k, n);
  }
  relu_l2norm_kernel<DOUT><<<nb, 256, 0, st>>>(g.Y, g.X, n);
}

void build_csr(const int* src, const int* dst, const GnnBufs& g, int n, int e, hipStream_t st) {
  hipMemsetAsync(g.cnt, 0, (size_t)n * 4, st);
  hist_kernel<<<(e + 255) / 256, 256, 0, st>>>(dst, g.cnt, e);
  norm_kernel<<<(n + 255) / 256, 256, 0, st>>>(g.cnt, g.nrm, n);
  exscan_kernel<<<1, 1024, 0, st>>>(g.cnt, g.rp, n);
  hipMemsetAsync(g.cur, 0, (size_t)n * 4, st);
  scatter_kernel<<<(e + 255) / 256, 256, 0, st>>>(src, dst, g.rp, g.cur, g.col, e);
}

} // namespace

extern "C" void kernel_launch(void* const* d_in, const int* in_sizes, int n_in,
                              void* d_out, int out_size, void* d_ws, size_t ws_size,
                              hipStream_t stream) {
  (void)in_sizes; (void)n_in; (void)out_size;

  const float* prot_x = (const float*)d_in[0];
  const float* lig_x  = (const float*)d_in[1];
  const float* pW[3] = {(const float*)d_in[2], (const float*)d_in[4], (const float*)d_in[6]};
  const float* pB[3] = {(const float*)d_in[3], (const float*)d_in[5], (const float*)d_in[7]};
  const float* lW[4] = {(const float*)d_in[8], (const float*)d_in[10], (const float*)d_in[12], (const float*)d_in[14]};
  const float* lB[4] = {(const float*)d_in[9], (const float*)d_in[11], (const float*)d_in[13], (const float*)d_in[15]};
  const float* qkv_w = (const float*)d_in[16];
  const float* qkv_b = (const float*)d_in[17];
  const float* proj_w = (const float*)d_in[18];
  const float* proj_b = (const float*)d_in[19];
  const float* h0_w = (const float*)d_in[20];
  const float* h0_b = (const float*)d_in[21];
  const float* h1_w = (const float*)d_in[22];
  const float* h1_b = (const float*)d_in[23];
  const float* h2_w = (const float*)d_in[24];
  const float* h2_b = (const float*)d_in[25];
  const float* fc_w = (const float*)d_in[26];
  const float* fc_b = (const float*)d_in[27];
  const int* prot_src = (const int*)d_in[28];
  const int* prot_dst = (const int*)d_in[29];
  const int* prot_gid = (const int*)d_in[30];
  const int* lig_src  = (const int*)d_in[31];
  const int* lig_dst  = (const int*)d_in[32];
  const int* lig_gid  = (const int*)d_in[33];

  // workspace carve-up
  char* w = (char*)d_ws;
  size_t off = 0;
  auto alloc = [&](size_t bytes) -> void* {
    void* p = w + off;
    off += (bytes + 255) & ~(size_t)255;
    return p;
  };
  float* A   = (float*)alloc((size_t)NPROT * 74 * 4);
  float* Bf  = (float*)alloc((size_t)NPROT * 74 * 4);
  float* X   = (float*)alloc((size_t)NPROT * 50 * 4);
  float* Y   = (float*)alloc((size_t)NPROT * 50 * 4);
  float* nrm = (float*)alloc((size_t)NPROT * 4);
  int* cnt   = (int*)alloc((size_t)NPROT * 4);
  int* cur   = (int*)alloc((size_t)NPROT * 4);
  int* rp    = (int*)alloc(((size_t)NPROT + 1) * 4);
  int* colb  = (int*)alloc((size_t)EPROT * 4);
  float* rep = (float*)alloc((size_t)65 * 45 * 4);
  float* qkvb = (float*)alloc((size_t)130 * 135 * 4);
  float* ctx  = (float*)alloc((size_t)5850 * 4);
  float* hb0  = (float*)alloc((size_t)2000 * 4);
  float* hb1  = (float*)alloc((size_t)1000 * 4);
  float* hb2  = (float*)alloc((size_t)500 * 4);
  if (off > ws_size) return;  // workspace too small: fail loudly via validation

  hipMemsetAsync(rep, 0, (size_t)65 * 45 * 4, stream);

  GnnBufs g{A, Bf, X, Y, nrm, cnt, cur, rp, colb};

  // ---- protein GNN ----
  build_csr(prot_src, prot_dst, g, NPROT, EPROT, stream);
  run_layer<74, 50>(prot_x, g, pW[0], pB[0], NPROT, stream);
  run_layer<50, 45>(g.X, g, pW[1], pB[1], NPROT, stream);
  run_layer<45, 45>(g.X, g, pW[2], pB[2], NPROT, stream);
  segmax_kernel<<<(NPROT * 45 + 255) / 256, 256, 0, stream>>>(g.X, prot_gid, rep, NPROT, 1);

  // ---- ligand GNN (reuses buffers) ----
  build_csr(lig_src, lig_dst, g, NLIG, ELIG, stream);
  run_layer<74, 50>(lig_x, g, lW[0], lB[0], NLIG, stream);
  run_layer<50, 45>(g.X, g, lW[1], lB[1], NLIG, stream);
  run_layer<45, 45>(g.X, g, lW[2], lB[2], NLIG, stream);
  run_layer<45, 45>(g.X, g, lW[3], lB[3], NLIG, stream);
  segmax_kernel<<<(NLIG * 45 + 255) / 256, 256, 0, stream>>>(g.X, lig_gid, rep, NLIG, 0);

  // ---- attention ----
  qkv_kernel<<<130, 256, 0, stream>>>(rep, qkv_w, qkv_b, qkvb);
  attn_kernel<<<130, 256, 0, stream>>>(qkvb, proj_w, proj_b, ctx);

  // ---- head MLP (split-K GEMV, bias pre-init, relu folded into next load) ----
  bias_init_kernel<<<8, 256, 0, stream>>>(h0_b, hb0, 2000);
  fc_splitk_kernel<false><<<dim3(8, 8), 256, 0, stream>>>(ctx, h0_w, hb0, 5850, 2000, 732);
  bias_init_kernel<<<4, 256, 0, stream>>>(h1_b, hb1, 1000);
  fc_splitk_kernel<true><<<dim3(4, 4), 256, 0, stream>>>(hb0, h1_w, hb1, 2000, 1000, 500);
  bias_init_kernel<<<2, 256, 0, stream>>>(h2_b, hb2, 500);
  fc_splitk_kernel<true><<<dim3(2, 2), 256, 0, stream>>>(hb1, h2_w, hb2, 1000, 500, 500);
  final_fc_kernel<<<1, 512, 0, stream>>>(hb2, fc_w, fc_b, (float*)d_out);
}

// Round 2
// 2895.956 us; speedup vs baseline: 1.5561x; 1.5561x over previous
//
#include <hip/hip_runtime.h>
#include <cstddef>
#include <cstdint>

namespace {

constexpr int NPROT = 100000;
constexpr int EPROT = 1600000;
constexpr int NLIG  = 5000;
constexpr int ELIG  = 80000;

// ---------------- CSR construction ----------------

__global__ void hist_kernel(const int* __restrict__ dst, int* __restrict__ cnt, int e) {
  int i = blockIdx.x * 256 + threadIdx.x;
  if (i < e) atomicAdd(&cnt[dst[i]], 1);
}

__global__ void norm_kernel(const int* __restrict__ cnt, float* __restrict__ nrm, int n) {
  int i = blockIdx.x * 256 + threadIdx.x;
  if (i < n) nrm[i] = 1.0f / sqrtf(fmaxf((float)cnt[i], 1.0f));
}

// single-block exclusive scan (n up to ~1M is fine; each thread owns a chunk)
__global__ void exscan_kernel(const int* __restrict__ in, int* __restrict__ out, int n) {
  __shared__ int sums[1024];
  int t = threadIdx.x;
  int chunk = (n + 1023) >> 10;
  int beg = t * chunk;
  int end = beg + chunk; if (end > n) end = n;
  int s = 0;
  for (int i = beg; i < end; ++i) s += in[i];
  sums[t] = s;
  __syncthreads();
  int val = s;
  for (int off = 1; off < 1024; off <<= 1) {
    int add = (t >= off) ? sums[t - off] : 0;
    __syncthreads();
    val += add;
    sums[t] = val;
    __syncthreads();
  }
  int run = val - s;  // exclusive prefix of this thread's chunk
  for (int i = beg; i < end; ++i) { out[i] = run; run += in[i]; }
  if (t == 1023) out[n] = val;
}

__global__ void scatter_kernel(const int* __restrict__ src, const int* __restrict__ dst,
                               const int* __restrict__ rp, int* __restrict__ cur,
                               int* __restrict__ col, int e) {
  int i = blockIdx.x * 256 + threadIdx.x;
  if (i < e) {
    int d = dst[i];
    int p = rp[d] + atomicAdd(&cur[d], 1);
    col[p] = src[i];
  }
}

// ---------------- GNN kernels ----------------
// Carry g_k = norm .* h_k.  Hop: s_k[v] = sum_{e: dst=v} g_{k-1}[src[e]]
//   h_k = norm .* s_k ;  g_k = norm^2 .* s_k
// y = b + sum_k h_k @ W[k*din:(k+1)*din]

// one wave (64 lanes) per node, lane = feature; 4 nodes per 256-thread block.
// 4-way unrolled edge loop: 4 independent col loads + 4 independent row loads
// in flight per iteration to cover LLC/L2 latency.
template<int DIN>
__global__ void gather_kernel(const float* __restrict__ g, const int* __restrict__ rp,
                              const int* __restrict__ col, float* __restrict__ outb, int n) {
  int wv = threadIdx.x >> 6, lane = threadIdx.x & 63;
  int v = blockIdx.x * 4 + wv;
  if (v >= n) return;
  int beg = rp[v], end = rp[v + 1];
  float a0 = 0.f, a1 = 0.f, b0 = 0.f, b1 = 0.f;
  float c0 = 0.f, c1 = 0.f, d0 = 0.f, d1 = 0.f;
  int e = beg;
  for (; e + 4 <= end; e += 4) {
    int s0 = col[e], s1 = col[e + 1], s2 = col[e + 2], s3 = col[e + 3];
    const float* r0 = g + (size_t)s0 * DIN;
    const float* r1 = g + (size_t)s1 * DIN;
    const float* r2 = g + (size_t)s2 * DIN;
    const float* r3 = g + (size_t)s3 * DIN;
    if (lane < DIN) { a0 += r0[lane]; b0 += r1[lane]; c0 += r2[lane]; d0 += r3[lane]; }
    if (DIN > 64) {
      if (lane + 64 < DIN) { a1 += r0[lane + 64]; b1 += r1[lane + 64]; c1 += r2[lane + 64]; d1 += r3[lane + 64]; }
    }
  }
  for (; e < end; ++e) {
    int s0 = col[e];
    const float* r0 = g + (size_t)s0 * DIN;
    if (lane < DIN) a0 += r0[lane];
    if (DIN > 64) { if (lane + 64 < DIN) a1 += r0[lane + 64]; }
  }
  a0 += b0 + c0 + d0;
  a1 += b1 + c1 + d1;
  float* o = outb + (size_t)v * DIN;
  if (lane < DIN) o[lane] = a0;
  if (DIN > 64) { if (lane + 64 < DIN) o[lane + 64] = a1; }
}

// fused: read src row (s_k, or x for INIT), write g into A, accumulate y += h @ W_k.
// FINAL: instead of writing y, apply relu + row-l2norm in-register and write X.
template<int DIN, int DOUT, bool INIT, bool WRITEG, bool FINAL>
__global__ void hop_gemm_kernel(const float* __restrict__ src, const float* __restrict__ nrm,
                                const float* __restrict__ W, const float* __restrict__ bias,
                                float* __restrict__ A, float* __restrict__ y,
                                float* __restrict__ Xout, int k, int n) {
  __shared__ float h[4][DIN];
  int wv = threadIdx.x >> 6, lane = threadIdx.x & 63;
  int v = blockIdx.x * 4 + wv;
  bool ok = (v < n);
  float nm = ok ? nrm[v] : 0.f;
  if (ok) {
    const float* srow = src + (size_t)v * DIN;
    for (int f = lane; f < DIN; f += 64) {
      float s = srow[f];
      float hv = INIT ? s : s * nm;
      h[wv][f] = hv;
      if (WRITEG) A[(size_t)v * DIN + f] = INIT ? s * nm : hv * nm;
    }
  }
  __syncthreads();
  float acc = 0.f;
  if (ok && lane < DOUT) {
    acc = INIT ? bias[lane] : y[(size_t)v * DOUT + lane];
    const float* Wk = W + (size_t)k * DIN * DOUT + lane;
    #pragma unroll 2
    for (int f = 0; f < DIN; ++f)
      acc += h[wv][f] * Wk[(size_t)f * DOUT];
  }
  if (FINAL) {
    float val = (ok && lane < DOUT) ? fmaxf(acc, 0.f) : 0.f;
    float ss = val * val;
    #pragma unroll
    for (int off = 32; off > 0; off >>= 1) ss += __shfl_xor(ss, off, 64);
    float scale = 1.f / fmaxf(sqrtf(ss), 1e-12f);
    if (ok && lane < DOUT) Xout[(size_t)v * DOUT + lane] = val * scale;
  } else {
    if (ok && lane < DOUT) y[(size_t)v * DOUT + lane] = acc;
  }
}

// hierarchical segment-max: block-local LDS max over 256 contiguous nodes
// (gids contiguous in this dataset; out-of-range rel falls back to a direct
// global atomic, so correctness holds for arbitrary gid). Values are >= 0
// post relu+l2norm, so uint atomicMax == float max; rep must be zeroed.
__global__ void segmax_kernel(const float* __restrict__ X, const int* __restrict__ gid,
                              float* __restrict__ rep, int n, int row_off) {
  __shared__ float tab[4][45];
  __shared__ int gids[256];
  int t = threadIdx.x;
  for (int i = t; i < 4 * 45; i += 256) ((float*)tab)[i] = 0.f;
  int v0 = blockIdx.x * 256;
  int vend = v0 + 256; if (vend > n) vend = n;
  int nv = vend - v0;
  if (t < nv) gids[t] = gid[v0 + t];
  __syncthreads();
  int g0 = gids[0];
  int total = nv * 45;
  for (int i = t; i < total; i += 256) {
    int vl = i / 45, j = i - vl * 45;
    float val = X[(size_t)(v0 + vl) * 45 + j];
    int rel = gids[vl] - g0;
    if (rel >= 0 && rel < 4)
      atomicMax((unsigned int*)&tab[rel][j], __float_as_uint(val));
    else
      atomicMax((unsigned int*)&rep[(size_t)(row_off + gids[vl]) * 45 + j], __float_as_uint(val));
  }
  __syncthreads();
  for (int i = t; i < 4 * 45; i += 256) {
    float val = ((float*)tab)[i];
    if (val > 0.f) {
      int rel = i / 45, j = i - rel * 45;
      atomicMax((unsigned int*)&rep[(size_t)(row_off + g0 + rel) * 45 + j], __float_as_uint(val));
    }
  }
}

// ---------------- attention ----------------

__global__ void qkv_kernel(const float* __restrict__ rep, const float* __restrict__ w,
                           const float* __restrict__ b, float* __restrict__ qkv) {
  int i = blockIdx.x;      // 0..129
  int t = threadIdx.x;     // 256
  __shared__ float sr[45];
  if (t < 45) sr[t] = (i < 65) ? rep[(size_t)i * 45 + t] : 0.f;
  __syncthreads();
  if (t < 135) {
    float acc = b[t];
    #pragma unroll 5
    for (int d = 0; d < 45; ++d) acc += sr[d] * w[d * 135 + t];
    qkv[(size_t)i * 135 + t] = acc;
  }
}

__global__ void attn_kernel(const float* __restrict__ qkv, const float* __restrict__ proj_w,
                            const float* __restrict__ proj_b, float* __restrict__ ctx) {
  int i = blockIdx.x;     // query row
  int t = threadIdx.x;    // 256
  __shared__ float q[45];
  __shared__ float p[130];
  __shared__ float red[256];
  __shared__ float ao[45];
  if (t < 45) q[t] = qkv[(size_t)i * 135 + t];
  __syncthreads();
  float s = -1e30f;
  if (t < 130) {
    int j = t;
    float dot = 0.f;
    #pragma unroll 5
    for (int d = 0; d < 45; ++d) dot += q[d] * qkv[(size_t)j * 135 + 45 + d];
    dot *= 0.14907119849998599f;  // 45^-0.5
    bool mz;  // mask == 0 ?
    if (i == 64 && j == 64) mz = true;
    else if (i == 64 || j == 64) mz = false;
    else mz = !(i == j && i < 65);
    s = mz ? -1e9f : dot;
  }
  red[t] = s;
  __syncthreads();
  #pragma unroll
  for (int off = 128; off > 0; off >>= 1) {
    if (t < off) red[t] = fmaxf(red[t], red[t + off]);
    __syncthreads();
  }
  float mx = red[0];
  __syncthreads();
  float e = (t < 130) ? expf(s - mx) : 0.f;
  red[t] = e;
  __syncthreads();
  #pragma unroll
  for (int off = 128; off > 0; off >>= 1) {
    if (t < off) red[t] += red[t + off];
    __syncthreads();
  }
  float denom = red[0];
  __syncthreads();
  if (t < 130) p[t] = e / denom;
  __syncthreads();
  if (t < 45) {
    float acc = 0.f;
    for (int j = 0; j < 130; ++j) acc += p[j] * qkv[(size_t)j * 135 + 90 + t];
    ao[t] = acc;
  }
  __syncthreads();
  if (t < 45) {
    float pr = proj_b[t];
    #pragma unroll 5
    for (int e2 = 0; e2 < 45; ++e2) pr += ao[e2] * proj_w[e2 * 45 + t];
    ctx[(size_t)i * 45 + t] = pr;
  }
}

// ---------------- head MLP ----------------

__global__ void bias_init_kernel(const float* __restrict__ b, float* __restrict__ out, int n) {
  int i = blockIdx.x * 256 + threadIdx.x;
  if (i < n) out[i] = b[i];
}

template<bool RELU_IN>
__global__ void fc_splitk_kernel(const float* __restrict__ x, const float* __restrict__ W,
                                 float* __restrict__ out, int nin, int nout, int kchunk) {
  __shared__ float xs[1024];
  int k0 = blockIdx.y * kchunk;
  int k1 = k0 + kchunk; if (k1 > nin) k1 = nin;
  int len = k1 - k0;
  for (int i = threadIdx.x; i < len; i += blockDim.x) {
    float v = x[k0 + i];
    xs[i] = RELU_IN ? fmaxf(v, 0.f) : v;
  }
  __syncthreads();
  int j = blockIdx.x * blockDim.x + threadIdx.x;
  if (j < nout) {
    float acc = 0.f;
    const float* Wp = W + (size_t)k0 * nout + j;
    for (int i = 0; i < len; ++i) acc += xs[i] * Wp[(size_t)i * nout];
    atomicAdd(&out[j], acc);
  }
}

__global__ void final_fc_kernel(const float* __restrict__ x, const float* __restrict__ W,
                                const float* __restrict__ b, float* __restrict__ out) {
  __shared__ float red[512];
  int t = threadIdx.x;
  float acc = 0.f;
  if (t < 500) acc = fmaxf(x[t], 0.f) * W[t];
  red[t] = acc;
  __syncthreads();
  #pragma unroll
  for (int off = 256; off > 0; off >>= 1) {
    if (t < off) red[t] += red[t + off];
    __syncthreads();
  }
  if (t == 0) {
    float z = red[0] + b[0];
    out[0] = 1.f / (1.f + expf(-z));
  }
}

// ---------------- host-side orchestration ----------------

struct GnnBufs {
  float *A, *B, *X, *Y, *nrm;
  int *cnt, *cur, *rp, *col;
};

template<int DIN, int DOUT>
void run_layer(const float* xin, const GnnBufs& g, const float* W, const float* b,
               int n, hipStream_t st) {
  int nb = (n + 3) / 4;
  hop_gemm_kernel<DIN, DOUT, true, true, false><<<nb, 256, 0, st>>>(xin, g.nrm, W, b, g.A, g.Y, g.X, 0, n);
  for (int k = 1; k <= 4; ++k) {
    gather_kernel<DIN><<<nb, 256, 0, st>>>(g.A, g.rp, g.col, g.B, n);
    if (k < 4)
      hop_gemm_kernel<DIN, DOUT, false, true, false><<<nb, 256, 0, st>>>(g.B, g.nrm, W, b, g.A, g.Y, g.X, k, n);
    else
      hop_gemm_kernel<DIN, DOUT, false, false, true><<<nb, 256, 0, st>>>(g.B, g.nrm, W, b, g.A, g.Y, g.X, 4, n);
  }
}

void build_csr(const int* src, const int* dst, const GnnBufs& g, int n, int e, hipStream_t st) {
  hipMemsetAsync(g.cnt, 0, (size_t)n * 4, st);
  hist_kernel<<<(e + 255) / 256, 256, 0, st>>>(dst, g.cnt, e);
  norm_kernel<<<(n + 255) / 256, 256, 0, st>>>(g.cnt, g.nrm, n);
  exscan_kernel<<<1, 1024, 0, st>>>(g.cnt, g.rp, n);
  hipMemsetAsync(g.cur, 0, (size_t)n * 4, st);
  scatter_kernel<<<(e + 255) / 256, 256, 0, st>>>(src, dst, g.rp, g.cur, g.col, e);
}

} // namespace

extern "C" void kernel_launch(void* const* d_in, const int* in_sizes, int n_in,
                              void* d_out, int out_size, void* d_ws, size_t ws_size,
                              hipStream_t stream) {
  (void)in_sizes; (void)n_in; (void)out_size;

  const float* prot_x = (const float*)d_in[0];
  const float* lig_x  = (const float*)d_in[1];
  const float* pW[3] = {(const float*)d_in[2], (const float*)d_in[4], (const float*)d_in[6]};
  const float* pB[3] = {(const float*)d_in[3], (const float*)d_in[5], (const float*)d_in[7]};
  const float* lW[4] = {(const float*)d_in[8], (const float*)d_in[10], (const float*)d_in[12], (const float*)d_in[14]};
  const float* lB[4] = {(const float*)d_in[9], (const float*)d_in[11], (const float*)d_in[13], (const float*)d_in[15]};
  const float* qkv_w = (const float*)d_in[16];
  const float* qkv_b = (const float*)d_in[17];
  const float* proj_w = (const float*)d_in[18];
  const float* proj_b = (const float*)d_in[19];
  const float* h0_w = (const float*)d_in[20];
  const float* h0_b = (const float*)d_in[21];
  const float* h1_w = (const float*)d_in[22];
  const float* h1_b = (const float*)d_in[23];
  const float* h2_w = (const float*)d_in[24];
  const float* h2_b = (const float*)d_in[25];
  const float* fc_w = (const float*)d_in[26];
  const float* fc_b = (const float*)d_in[27];
  const int* prot_src = (const int*)d_in[28];
  const int* prot_dst = (const int*)d_in[29];
  const int* prot_gid = (const int*)d_in[30];
  const int* lig_src  = (const int*)d_in[31];
  const int* lig_dst  = (const int*)d_in[32];
  const int* lig_gid  = (const int*)d_in[33];

  // workspace carve-up
  char* w = (char*)d_ws;
  size_t off = 0;
  auto alloc = [&](size_t bytes) -> void* {
    void* p = w + off;
    off += (bytes + 255) & ~(size_t)255;
    return p;
  };
  float* A   = (float*)alloc((size_t)NPROT * 74 * 4);
  float* Bf  = (float*)alloc((size_t)NPROT * 74 * 4);
  float* X   = (float*)alloc((size_t)NPROT * 50 * 4);
  float* Y   = (float*)alloc((size_t)NPROT * 50 * 4);
  float* nrm = (float*)alloc((size_t)NPROT * 4);
  int* cnt   = (int*)alloc((size_t)NPROT * 4);
  int* cur   = (int*)alloc((size_t)NPROT * 4);
  int* rp    = (int*)alloc(((size_t)NPROT + 1) * 4);
  int* colb  = (int*)alloc((size_t)EPROT * 4);
  float* rep = (float*)alloc((size_t)65 * 45 * 4);
  float* qkvb = (float*)alloc((size_t)130 * 135 * 4);
  float* ctx  = (float*)alloc((size_t)5850 * 4);
  float* hb0  = (float*)alloc((size_t)2000 * 4);
  float* hb1  = (float*)alloc((size_t)1000 * 4);
  float* hb2  = (float*)alloc((size_t)500 * 4);
  if (off > ws_size) return;  // workspace too small: fail loudly via validation

  hipMemsetAsync(rep, 0, (size_t)65 * 45 * 4, stream);

  GnnBufs g{A, Bf, X, Y, nrm, cnt, cur, rp, colb};

  // ---- protein GNN ----
  build_csr(prot_src, prot_dst, g, NPROT, EPROT, stream);
  run_layer<74, 50>(prot_x, g, pW[0], pB[0], NPROT, stream);
  run_layer<50, 45>(g.X, g, pW[1], pB[1], NPROT, stream);
  run_layer<45, 45>(g.X, g, pW[2], pB[2], NPROT, stream);
  segmax_kernel<<<(NPROT + 255) / 256, 256, 0, stream>>>(g.X, prot_gid, rep, NPROT, 1);

  // ---- ligand GNN (reuses buffers) ----
  build_csr(lig_src, lig_dst, g, NLIG, ELIG, stream);
  run_layer<74, 50>(lig_x, g, lW[0], lB[0], NLIG, stream);
  run_layer<50, 45>(g.X, g, lW[1], lB[1], NLIG, stream);
  run_layer<45, 45>(g.X, g, lW[2], lB[2], NLIG, stream);
  run_layer<45, 45>(g.X, g, lW[3], lB[3], NLIG, stream);
  segmax_kernel<<<(NLIG + 255) / 256, 256, 0, stream>>>(g.X, lig_gid, rep, NLIG, 0);

  // ---- attention ----
  qkv_kernel<<<130, 256, 0, stream>>>(rep, qkv_w, qkv_b, qkvb);
  attn_kernel<<<130, 256, 0, stream>>>(qkvb, proj_w, proj_b, ctx);

  // ---- head MLP (split-K GEMV, bias pre-init, relu folded into next load) ----
  bias_init_kernel<<<8, 256, 0, stream>>>(h0_b, hb0, 2000);
  fc_splitk_kernel<false><<<dim3(8, 8), 256, 0, stream>>>(ctx, h0_w, hb0, 5850, 2000, 732);
  bias_init_kernel<<<4, 256, 0, stream>>>(h1_b, hb1, 1000);
  fc_splitk_kernel<true><<<dim3(4, 4), 256, 0, stream>>>(hb0, h1_w, hb1, 2000, 1000, 500);
  bias_init_kernel<<<2, 256, 0, stream>>>(h2_b, hb2, 500);
  fc_splitk_kernel<true><<<dim3(2, 2), 256, 0, stream>>>(hb1, h2_w, hb2, 1000, 500, 500);
  final_fc_kernel<<<1, 512, 0, stream>>>(hb2, fc_w, fc_b, (float*)d_out);
}